// Round 11
// baseline (1555.937 us; speedup 1.0000x reference)
//
#include <hip/hip_runtime.h>

#define BS    32
#define MDIM  256
#define NDIM  512
#define ITERS 1000
#define WPB   4      // wgs per batch; each owns 128 rows of G
#define RPW   128
#define BLK   512
#define ALPHA 0.02f
#define BETA  0.02f

// ---- LDS (floats) ----
#define ATS      516                    // prologue A-tile block stride
#define ATILE_FL (32 * ATS)             // 16512
#define WBUF_OFF ATILE_FL               // w staged: 2 parities x 32 blk x 20
#define WBLK     20
#define C_OFF    (WBUF_OFF + 2 * 32 * WBLK)
#define BT_OFF   (C_OFF + RPW)
#define SMEM_FL  (BT_OFF + 32)          // ~71.8 KB

// Exchange slab [2 parity][BS][512] floats, mantissa-tagged (low 8 bits =
// (k+1)&255), relaxed agent-scope atomics. Proven R6/R7/R9. No fast paths.
#define SLAB_FL  (2 * BS * NDIM)

__device__ __forceinline__ unsigned ld_coh_u32(const void* p) {
  return __hip_atomic_load(reinterpret_cast<const unsigned*>(p),
                           __ATOMIC_RELAXED, __HIP_MEMORY_SCOPE_AGENT);
}
__device__ __forceinline__ void st_coh_u32(void* p, unsigned v) {
  __hip_atomic_store(reinterpret_cast<unsigned*>(p), v,
                     __ATOMIC_RELAXED, __HIP_MEMORY_SCOPE_AGENT);
}
__device__ __forceinline__ unsigned tagf(float v, unsigned tag) {
  return (__float_as_uint(v) & ~0xFFu) | tag;
}

__global__ __launch_bounds__(BLK, 1) void pdhg_kernel(
    const float* __restrict__ A, const float* __restrict__ Bvec,
    float* __restrict__ out, float* __restrict__ slab)
{
  __shared__ float smem[SMEM_FL];
  const int tid   = threadIdx.x;
  const int bid   = blockIdx.x;
  const int batch = bid & (BS - 1);
  const int slice = bid >> 5;          // 0..3
  const int i0    = slice * RPW;

  const int tj   = tid & 31;           // j-block [tj*16, +16)
  const int ti   = tid >> 5;           // i-block [i0+ti*8, +8)
  const int lane = tid & 63;

  // ================= PROLOGUE: G = A^T A slice (regs), c = A^T b ==========
  float acc[8][16];
#pragma unroll
  for (int r = 0; r < 8; ++r)
#pragma unroll
    for (int s = 0; s < 16; ++s) acc[r][s] = 0.f;
  float cacc[8];
#pragma unroll
  for (int r = 0; r < 8; ++r) cacc[r] = 0.f;

  const float* Ag = A + (size_t)batch * MDIM * NDIM;

  for (int mt = 0; mt < MDIM / 32; ++mt) {
#pragma unroll 4
    for (int q = 0; q < 8; ++q) {
      int f  = q * 512 + tid;
      int mm = f >> 7;
      int j  = (f & 127) << 2;
      float4 v = *reinterpret_cast<const float4*>(
          Ag + (size_t)(mt * 32 + mm) * NDIM + j);
      *reinterpret_cast<float4*>(
          &smem[(j >> 4) * ATS + mm * 16 + (j & 15)]) = v;
    }
    if (tid < 32) smem[BT_OFF + tid] = Bvec[batch * MDIM + mt * 32 + tid];
    __syncthreads();

    const int ibase = ((i0 + 8 * ti) >> 4) * ATS + ((8 * ti) & 15);
    const int jbase = tj * ATS;
    for (int mm = 0; mm < 32; ++mm) {
      float4 a0 = *reinterpret_cast<const float4*>(&smem[ibase + mm * 16]);
      float4 a1 = *reinterpret_cast<const float4*>(&smem[ibase + mm * 16 + 4]);
      float ai[8] = {a0.x, a0.y, a0.z, a0.w, a1.x, a1.y, a1.z, a1.w};
      float aj[16];
#pragma unroll
      for (int kk = 0; kk < 4; ++kk) {
        float4 v = *reinterpret_cast<const float4*>(
            &smem[jbase + mm * 16 + 4 * kk]);
        aj[4*kk] = v.x; aj[4*kk+1] = v.y; aj[4*kk+2] = v.z; aj[4*kk+3] = v.w;
      }
#pragma unroll
      for (int r = 0; r < 8; ++r)
#pragma unroll
        for (int s = 0; s < 16; ++s) acc[r][s] = fmaf(ai[r], aj[s], acc[r][s]);
      if (tj == 0) {
        float bv = smem[BT_OFF + mm];
#pragma unroll
        for (int r = 0; r < 8; ++r) cacc[r] = fmaf(ai[r], bv, cacc[r]);
      }
    }
    __syncthreads();
  }
  if (tj == 0) {
#pragma unroll
    for (int r = 0; r < 8; ++r) smem[C_OFF + ti * 8 + r] = cacc[r];
  }
  __syncthreads();

  // ================= ITERATION (one barrier per iter) =====================
  // Reduce-output mapping: after the 5-stage butterfly, lane holds the full
  // row sum for r = 4*bit4 + 2*bit3 + bit2 of its ti-block; owners are the
  // (lane&3)==0 lanes (one per row).
  const int  r_of  = ((lane >> 4) & 1) * 4 + ((lane >> 3) & 1) * 2 +
                     ((lane >> 2) & 1);
  const int  i_loc = ti * 8 + r_of;              // 0..127
  const bool owner = (lane & 3) == 0;
  const float c_reg = smem[C_OFF + i_loc];
  float x = 0.f, t = 0.f;

  float* myslot = slab + batch * NDIM + i0 + i_loc;   // + parity*BS*NDIM
  const float* myrd = slab + batch * NDIM + tid;      // thread's 4B of w

  for (int k = 0; k < ITERS; ++k) {
    float xn = 0.f;
    if (owner) {
      float y = x - ALPHA * t;
      xn = fmaxf(y - ALPHA, 0.f) - fmaxf(-y - ALPHA, 0.f);
    }
    if (k == ITERS - 1) { x = xn; break; }

    const int par = (k & 1) * BS * NDIM;
    const unsigned tag = (unsigned)(k + 1) & 0xFFu;
    if (owner) {
      float wv_pub = 2.f * xn - x;
      x = xn;
      st_coh_u32(myslot + par, tagf(wv_pub, tag));
    }

    // poll this thread's 4B of w (self-validating mantissa tag)
    unsigned qq;
    do {
      qq = ld_coh_u32(myrd + par);
    } while ((qq ^ tag) & 0xFFu);

    // stage w into parity-double-buffered padded LDS (global j = tid)
    float* wst = &smem[WBUF_OFF + (k & 1) * (32 * WBLK)];
    wst[(tid >> 4) * WBLK + (tid & 15)] = __uint_as_float(qq);
    __syncthreads();   // the only barrier in the loop

    // G·w partials from register-resident G
    float wv[16];
    {
      const float* wb = &wst[tj * WBLK];
#pragma unroll
      for (int kk = 0; kk < 4; ++kk) {
        float4 v = *reinterpret_cast<const float4*>(wb + 4 * kk);
        wv[4*kk] = v.x; wv[4*kk+1] = v.y; wv[4*kk+2] = v.z; wv[4*kk+3] = v.w;
      }
    }
    float p[8];
#pragma unroll
    for (int r = 0; r < 8; ++r) {
      float pv = 0.f;
#pragma unroll
      for (int s = 0; s < 16; ++s) pv = fmaf(acc[r][s], wv[s], pv);
      p[r] = pv;
    }

    // 5-stage multi-value butterfly over the 32 tj-lanes (half-wave;
    // xor masks <=16 never cross the 32-lane halves)
    const bool b4 = (lane & 16), b3 = (lane & 8), b2 = (lane & 4);
    float n[4];
#pragma unroll
    for (int q = 0; q < 4; ++q) {
      float s_ = b4 ? p[q] : p[q + 4];
      float rv = __shfl_xor(s_, 16);
      n[q] = (b4 ? p[q + 4] : p[q]) + rv;
    }
    float m2[2];
#pragma unroll
    for (int q = 0; q < 2; ++q) {
      float s_ = b3 ? n[q] : n[q + 2];
      float rv = __shfl_xor(s_, 8);
      m2[q] = (b3 ? n[q + 2] : n[q]) + rv;
    }
    float v1;
    {
      float s_ = b2 ? m2[0] : m2[1];
      float rv = __shfl_xor(s_, 4);
      v1 = (b2 ? m2[1] : m2[0]) + rv;
    }
    v1 += __shfl_xor(v1, 2);
    v1 += __shfl_xor(v1, 1);

    if (owner) t += BETA * (v1 - c_reg);   // t_{k+1} = t_k + β(Gw_k − c)
  }

  // ---- epilogue: owners write x slice ----
  if (owner) out[(size_t)batch * NDIM + i0 + i_loc] = x;
}

extern "C" void kernel_launch(void* const* d_in, const int* in_sizes, int n_in,
                              void* d_out, int out_size, void* d_ws, size_t ws_size,
                              hipStream_t stream) {
  const float* A = (const float*)d_in[0];
  const float* b = (const float*)d_in[1];
  float* out  = (float*)d_out;
  float* slab = (float*)d_ws;                    // 128 KiB w-exchange slab

  hipMemsetAsync(d_ws, 0, SLAB_FL * sizeof(float), stream);  // tag 0 ≠ 1,2

  void* args[] = {(void*)&A, (void*)&b, (void*)&out, (void*)&slab};
  hipLaunchCooperativeKernel((const void*)pdhg_kernel, dim3(BS * WPB), dim3(BLK),
                             args, 0, stream);
}